// Round 4
// baseline (120.119 us; speedup 1.0000x reference)
//
#include <hip/hip_runtime.h>

// out[b,g] = sum_n x[b,g,n] * W[g,n] + bias[g]
// x: [16384, 368, 16] f32 (386 MB, streamed once, zero reuse)
// W: [368,16] f32 (23.5 KB, L1-resident), bias: [368] f32, out: [16384,368] f32 (24 MB)
//
// One lane = one output element o = b*368+g. Lane reads its full 16-float row
// (4x float4, NONTEMPORAL: zero-reuse stream must not evict L2/L3), dots with
// W[g] (cached loads), writes out[o] (consecutive lanes -> contiguous 256 B,
// nontemporal). No grid-stride loop, no shuffles. total = 6,029,312 = 23552*256.

#define NGROUPS 368

typedef float vfloat4 __attribute__((ext_vector_type(4)));  // native vector: OK for nontemporal builtins

__global__ __launch_bounds__(256) void ensemble_kernel(
    const vfloat4* __restrict__ x4,
    const vfloat4* __restrict__ w4,
    const float* __restrict__ bias,
    float* __restrict__ out,
    int total)
{
    const int o = blockIdx.x * 256 + threadIdx.x;
    if (o >= total) return;

    const int g = o % NGROUPS;            // magic-mul mod (W/bias index only)

    // x row: 4 independent nontemporal 16 B loads, in flight together
    const vfloat4* xp = x4 + ((size_t)o << 2);
    const vfloat4 x0 = __builtin_nontemporal_load(xp + 0);
    const vfloat4 x1 = __builtin_nontemporal_load(xp + 1);
    const vfloat4 x2 = __builtin_nontemporal_load(xp + 2);
    const vfloat4 x3 = __builtin_nontemporal_load(xp + 3);

    // W row: cached (hot in L1 across the whole CU)
    const vfloat4 w0 = w4[(g << 2) + 0];
    const vfloat4 w1 = w4[(g << 2) + 1];
    const vfloat4 w2 = w4[(g << 2) + 2];
    const vfloat4 w3 = w4[(g << 2) + 3];

    float s = x0.x * w0.x + x0.y * w0.y + x0.z * w0.z + x0.w * w0.w;
    s += x1.x * w1.x + x1.y * w1.y + x1.z * w1.z + x1.w * w1.w;
    s += x2.x * w2.x + x2.y * w2.y + x2.z * w2.z + x2.w * w2.w;
    s += x3.x * w3.x + x3.y * w3.y + x3.z * w3.z + x3.w * w3.w;

    __builtin_nontemporal_store(s + bias[g], out + o);
}

extern "C" void kernel_launch(void* const* d_in, const int* in_sizes, int n_in,
                              void* d_out, int out_size, void* d_ws, size_t ws_size,
                              hipStream_t stream)
{
    const vfloat4* x4  = (const vfloat4*)d_in[0];
    const vfloat4* w4  = (const vfloat4*)d_in[1];
    const float* bias  = (const float*)d_in[2];
    float* out = (float*)d_out;

    const int total = out_size;                  // 16384*368 = 6,029,312
    const int blocks = (total + 255) / 256;      // 23552 (exact)

    ensemble_kernel<<<blocks, 256, 0, stream>>>(x4, w4, bias, out, total);
}

// Round 5
// 78.074 us; speedup vs baseline: 1.5385x; 1.5385x over previous
//
#include <hip/hip_runtime.h>

// out[b,g] = sum_n x[b,g,n] * W[g,n] + bias[g]
// x: [16384, 368, 16] f32 (386 MB streamed once), W: [368,16] f32 (L1-hot),
// bias: [368] f32, out: [16384,368] f32 (24 MB).
//
// MLP probe: each thread owns rows o and o + R/2 (R/2 = 368*8192, so both
// rows have the SAME g -> one W row). All 8 global_load_dwordx4 issued
// back-to-back before any arithmetic -> 8 lines in flight per thread.
// Cached (no NT: R4 showed nt loads cost +35%). Coalesced 64 B/lane.

#define NGROUPS 368

typedef float vfloat4 __attribute__((ext_vector_type(4)));

__global__ __launch_bounds__(256) void ensemble_kernel(
    const vfloat4* __restrict__ x4,
    const vfloat4* __restrict__ w4,
    const float* __restrict__ bias,
    float* __restrict__ out,
    int half)                    // = total/2 = 3,014,656
{
    const int o = blockIdx.x * 256 + threadIdx.x;
    if (o >= half) return;
    const int o2 = o + half;     // same g: half % 368 == 0

    const int g = o % NGROUPS;

    // ---- issue all 8 loads first (8-deep MLP) ----
    const vfloat4* xp0 = x4 + ((size_t)o  << 2);
    const vfloat4* xp1 = x4 + ((size_t)o2 << 2);
    const vfloat4 a0 = xp0[0], a1 = xp0[1], a2 = xp0[2], a3 = xp0[3];
    const vfloat4 b0 = xp1[0], b1 = xp1[1], b2 = xp1[2], b3 = xp1[3];

    // W row + bias (cached, hot)
    const vfloat4 w0 = w4[(g << 2) + 0];
    const vfloat4 w1 = w4[(g << 2) + 1];
    const vfloat4 w2 = w4[(g << 2) + 2];
    const vfloat4 w3 = w4[(g << 2) + 3];
    const float bg = bias[g];

    float s0 = a0.x * w0.x + a0.y * w0.y + a0.z * w0.z + a0.w * w0.w;
    s0 += a1.x * w1.x + a1.y * w1.y + a1.z * w1.z + a1.w * w1.w;
    s0 += a2.x * w2.x + a2.y * w2.y + a2.z * w2.z + a2.w * w2.w;
    s0 += a3.x * w3.x + a3.y * w3.y + a3.z * w3.z + a3.w * w3.w;

    float s1 = b0.x * w0.x + b0.y * w0.y + b0.z * w0.z + b0.w * w0.w;
    s1 += b1.x * w1.x + b1.y * w1.y + b1.z * w1.z + b1.w * w1.w;
    s1 += b2.x * w2.x + b2.y * w2.y + b2.z * w2.z + b2.w * w2.w;
    s1 += b3.x * w3.x + b3.y * w3.y + b3.z * w3.z + b3.w * w3.w;

    out[o]  = s0 + bg;
    out[o2] = s1 + bg;
}

extern "C" void kernel_launch(void* const* d_in, const int* in_sizes, int n_in,
                              void* d_out, int out_size, void* d_ws, size_t ws_size,
                              hipStream_t stream)
{
    const vfloat4* x4  = (const vfloat4*)d_in[0];
    const vfloat4* w4  = (const vfloat4*)d_in[1];
    const float* bias  = (const float*)d_in[2];
    float* out = (float*)d_out;

    const int half = out_size / 2;               // 3,014,656 = 368*8192
    const int blocks = (half + 255) / 256;       // 11776 exact

    ensemble_kernel<<<blocks, 256, 0, stream>>>(x4, w4, bias, out, half);
}